// Round 4
// baseline (6876.254 us; speedup 1.0000x reference)
//
#include <hip/hip_runtime.h>
#include <hip/hip_bf16.h>

// Problem constants
#define S_LEN  1024
#define B_SZ   32
#define IN_DIM 3072
#define HID    256
#define NHEAD  16
#define HDIM   16
#define DFF    1024
#define NLAYER 4
#define NCLS   1623
#define EMB_D  10
#define MROWS  (S_LEN * B_SZ)   // 32768

// ---------------------------------------------------------------------------
// Generic tiled fp32 GEMM: C[M,N] = A[M,K] * W[N,:K]^T (+bias)(+relu)(+residual)
// W leading dim Wld (>= K) supports K-chunked weights.
// FLAGS: 1=bias, 2=relu, 4=residual add (R), 8=bf16 output
// BM=BN=128, BK=16, 256 threads, 8x8 per thread. M assumed multiple of 128.
// R/C intentionally NOT __restrict__: in-place residual (R==C) is used.
// ---------------------------------------------------------------------------
template<int FLAGS>
__global__ __launch_bounds__(256) void gemm_k(
    const float* __restrict__ A, const float* __restrict__ W,
    const float* __restrict__ bias, const float* R,
    void* C, int N, int K, int Wld)
{
    __shared__ float As[16][132];
    __shared__ float Ws[16][132];
    const int t  = threadIdx.x;
    const int bm = blockIdx.x * 128;
    const int bn = blockIdx.y * 128;
    const int tx = t & 15, ty = t >> 4;

    float acc[8][8];
#pragma unroll
    for (int i = 0; i < 8; ++i)
#pragma unroll
        for (int j = 0; j < 8; ++j) acc[i][j] = 0.f;

    for (int k0 = 0; k0 < K; k0 += 16) {
        const bool vec = ((K & 3) == 0) && (k0 + 16 <= K);
#pragma unroll
        for (int rep = 0; rep < 2; ++rep) {
            const int idx = t + rep * 256;       // 512 float4 slots per tile
            const int row = idx >> 2;
            const int c4  = (idx & 3) << 2;
            float va[4], vw[4];
            const float* asrc = A + (long)(bm + row) * K + k0 + c4;
            if (vec) {
                const float4 tmp = *(const float4*)asrc;
                va[0]=tmp.x; va[1]=tmp.y; va[2]=tmp.z; va[3]=tmp.w;
            } else {
#pragma unroll
                for (int j = 0; j < 4; ++j)
                    va[j] = (k0 + c4 + j < K) ? asrc[j] : 0.f;
            }
            const int wr = bn + row;
            const float* wsrc = W + (long)wr * Wld + k0 + c4;
            if (vec && wr < N) {
                const float4 tmp = *(const float4*)wsrc;
                vw[0]=tmp.x; vw[1]=tmp.y; vw[2]=tmp.z; vw[3]=tmp.w;
            } else {
#pragma unroll
                for (int j = 0; j < 4; ++j)
                    vw[j] = (wr < N && k0 + c4 + j < K) ? wsrc[j] : 0.f;
            }
#pragma unroll
            for (int j = 0; j < 4; ++j) {
                As[c4 + j][row] = va[j];
                Ws[c4 + j][row] = vw[j];
            }
        }
        __syncthreads();
#pragma unroll
        for (int kk = 0; kk < 16; ++kk) {
            float a[8], b[8];
#pragma unroll
            for (int i = 0; i < 8; ++i) a[i] = As[kk][ty * 8 + i];
#pragma unroll
            for (int j = 0; j < 8; ++j) b[j] = Ws[kk][tx * 8 + j];
#pragma unroll
            for (int i = 0; i < 8; ++i)
#pragma unroll
                for (int j = 0; j < 8; ++j)
                    acc[i][j] = fmaf(a[i], b[j], acc[i][j]);
        }
        __syncthreads();
    }

#pragma unroll
    for (int i = 0; i < 8; ++i) {
        const long r = bm + ty * 8 + i;
#pragma unroll
        for (int j = 0; j < 8; ++j) {
            const int c = bn + tx * 8 + j;
            if (c < N) {
                float v = acc[i][j];
                if (FLAGS & 1) v += bias[c];
                if (FLAGS & 2) v = fmaxf(v, 0.f);
                if (FLAGS & 4) v += R[r * N + c];
                if (FLAGS & 8) ((__hip_bfloat16*)C)[r * N + c] = __float2bfloat16(v);
                else           ((float*)C)[r * N + c] = v;
            }
        }
    }
}

// ---------------------------------------------------------------------------
// LayerNorm over last dim 256; one wave per row, 4 rows per block.
// ---------------------------------------------------------------------------
__global__ __launch_bounds__(256) void ln_k(
    const float* __restrict__ x, const float* __restrict__ g,
    const float* __restrict__ b, float* __restrict__ y)
{
    const int wave = threadIdx.x >> 6, lane = threadIdx.x & 63;
    const long row = (long)(blockIdx.x << 2) + wave;
    const float4 v = ((const float4*)(x + row * HID))[lane];
    float s = v.x + v.y + v.z + v.w;
#pragma unroll
    for (int m = 32; m; m >>= 1) s += __shfl_xor(s, m);
    const float mean = s * (1.f / 256.f);
    const float d0 = v.x - mean, d1 = v.y - mean, d2 = v.z - mean, d3 = v.w - mean;
    float ss = d0 * d0 + d1 * d1 + d2 * d2 + d3 * d3;
#pragma unroll
    for (int m = 32; m; m >>= 1) ss += __shfl_xor(ss, m);
    const float inv = rsqrtf(ss * (1.f / 256.f) + 1e-5f);
    const float4 gg = ((const float4*)g)[lane];
    const float4 bb = ((const float4*)b)[lane];
    float4 o;
    o.x = fmaf(d0 * inv, gg.x, bb.x);
    o.y = fmaf(d1 * inv, gg.y, bb.y);
    o.z = fmaf(d2 * inv, gg.z, bb.z);
    o.w = fmaf(d3 * inv, gg.w, bb.w);
    ((float4*)(y + row * HID))[lane] = o;
}

// ---------------------------------------------------------------------------
// Concat: hc[row] = [h0[row] (256), emb[fb[row]] (10)]; one wave per row.
// ---------------------------------------------------------------------------
__global__ __launch_bounds__(64) void concat_k(
    const float* __restrict__ h0, const float* __restrict__ emb,
    const int* __restrict__ fb, float* __restrict__ hc)
{
    const int row  = blockIdx.x;
    const int lane = threadIdx.x;
    const float4 v = ((const float4*)(h0 + (long)row * HID))[lane];
    float* dst = hc + (long)row * (HID + EMB_D) + lane * 4;
    float2 a; a.x = v.x; a.y = v.y;
    float2 c; c.x = v.z; c.y = v.w;
    *(float2*)dst = a;
    *(float2*)(dst + 2) = c;
    if (lane < EMB_D)
        hc[(long)row * (HID + EMB_D) + HID + lane] = emb[fb[row] * EMB_D + lane];
}

// ---------------------------------------------------------------------------
// qkvb prep (in-place): softmax over q[0:16] and k[16:32], sigmoid beta[48].
// 128 groups of 49 floats per block, staged via LDS for coalescing.
// ---------------------------------------------------------------------------
__global__ __launch_bounds__(128) void prep_k(float* __restrict__ qkvb)
{
    __shared__ float buf[128 * 49];
    const long base = (long)blockIdx.x * (128 * 49);
    for (int i = threadIdx.x; i < 128 * 49; i += 128) buf[i] = qkvb[base + i];
    __syncthreads();
    float* p = buf + threadIdx.x * 49;
#pragma unroll
    for (int seg = 0; seg < 2; ++seg) {
        float* qq = p + seg * 16;
        float mx = qq[0];
#pragma unroll
        for (int i = 1; i < 16; ++i) mx = fmaxf(mx, qq[i]);
        float e[16]; float sum = 0.f;
#pragma unroll
        for (int i = 0; i < 16; ++i) { e[i] = __expf(qq[i] - mx); sum += e[i]; }
        const float r = 1.f / sum;
#pragma unroll
        for (int i = 0; i < 16; ++i) qq[i] = e[i] * r;
    }
    p[48] = 1.f / (1.f + __expf(-p[48]));
    __syncthreads();
    for (int i = threadIdx.x; i < 128 * 49; i += 128) qkvb[base + i] = buf[i];
}

// ---------------------------------------------------------------------------
// Delta-rule scan: one wave per (b,h). Lane l: vi=l>>2, kg=l&3 holds
// W[kg*4+j][vi], j=0..3. q/k/beta already softmax/sigmoid'ed by prep_k.
// Next-step loads issued before the dependent chain (prefetch).
// ---------------------------------------------------------------------------
__global__ __launch_bounds__(64) void scan_k(
    const float* __restrict__ qkvb, float* __restrict__ o)
{
    const int b  = blockIdx.x >> 4;
    const int hh = blockIdx.x & 15;
    const int lane = threadIdx.x;
    const int vi = lane >> 2, kg = lane & 3;
    const long gstride = (long)B_SZ * NHEAD * 49;       // per-s stride
    const float* pb = qkvb + ((long)b * NHEAD + hh) * 49;
    float* po = o + (long)b * HID + hh * HDIM + vi;

    float W[4] = {0.f, 0.f, 0.f, 0.f};
    float q[4], k[4], vt, bt;
#pragma unroll
    for (int j = 0; j < 4; ++j) { q[j] = pb[kg * 4 + j]; k[j] = pb[16 + kg * 4 + j]; }
    vt = pb[32 + vi];
    bt = pb[48];

    for (int s = 0; s < S_LEN; ++s) {
        float nq[4], nk[4], nvt, nbt;
        if (s + 1 < S_LEN) {
            const float* p = pb + (long)(s + 1) * gstride;
#pragma unroll
            for (int j = 0; j < 4; ++j) { nq[j] = p[kg * 4 + j]; nk[j] = p[16 + kg * 4 + j]; }
            nvt = p[32 + vi];
            nbt = p[48];
        } else {
            nq[0]=nq[1]=nq[2]=nq[3]=0.f; nk[0]=nk[1]=nk[2]=nk[3]=0.f; nvt=0.f; nbt=0.f;
        }
        // v_old = W^T k  (reduce over 16 k: 4 local + quad butterfly)
        float vo = 0.f;
#pragma unroll
        for (int j = 0; j < 4; ++j) vo = fmaf(W[j], k[j], vo);
        vo += __shfl_xor(vo, 1);
        vo += __shfl_xor(vo, 2);
        const float dv = bt * (vt - vo);              // v_new - v_old
#pragma unroll
        for (int j = 0; j < 4; ++j) W[j] = fmaf(k[j], dv, W[j]);
        // o = W_new^T q
        float ov = 0.f;
#pragma unroll
        for (int j = 0; j < 4; ++j) ov = fmaf(W[j], q[j], ov);
        ov += __shfl_xor(ov, 1);
        ov += __shfl_xor(ov, 2);
        if (kg == 0) po[(long)s * (B_SZ * HID)] = ov;
#pragma unroll
        for (int j = 0; j < 4; ++j) { q[j] = nq[j]; k[j] = nk[j]; }
        vt = nvt; bt = nbt;
    }
}

// ---------------------------------------------------------------------------
extern "C" void kernel_launch(void* const* d_in, const int* in_sizes, int n_in,
                              void* d_out, int out_size, void* d_ws, size_t ws_size,
                              hipStream_t stream)
{
    const float* x      = (const float*)d_in[0];
    const int*   fb     = (const int*)  d_in[1];
    const float* fc1_w  = (const float*)d_in[2];
    const float* fc1_b  = (const float*)d_in[3];
    const float* emb    = (const float*)d_in[4];
    const float* proj_w = (const float*)d_in[5];
    const float* proj_b = (const float*)d_in[6];
    const float* ln1_g  = (const float*)d_in[7];
    const float* ln1_b  = (const float*)d_in[8];
    const float* slow_w = (const float*)d_in[9];
    const float* out_w  = (const float*)d_in[10];
    const float* ln2_g  = (const float*)d_in[11];
    const float* ln2_b  = (const float*)d_in[12];
    const float* ff1_w  = (const float*)d_in[13];
    const float* ff1_b  = (const float*)d_in[14];
    const float* ff2_w  = (const float*)d_in[15];
    const float* ff2_b  = (const float*)d_in[16];
    const float* outl_w = (const float*)d_in[17];
    const float* outl_b = (const float*)d_in[18];

    // Workspace: h and y (67 MB) in d_ws. Big transients in d_out scratch:
    //   hcat 34.9MB, qkvb 102.8MB, hff half 67.1MB. Output is FP32
    //   (53.2M floats = 212.9MB), fully overwritten by the final GEMM.
    float* h  = (float*)d_ws;
    float* y  = h + (size_t)MROWS * HID;
    float* sc = (float*)d_out;

    const dim3 blk(256);

    // fc1: y = x @ fc1_w^T + fc1_b          (N=256, K=3072)
    gemm_k<1><<<dim3(MROWS/128, 2), blk, 0, stream>>>(x, fc1_w, fc1_b, nullptr, y, HID, IN_DIM, IN_DIM);
    // hcat = [y, emb[fb]]  -> d_out scratch
    concat_k<<<dim3(MROWS), dim3(64), 0, stream>>>(y, emb, fb, sc);
    // proj: h = hcat @ proj_w^T + proj_b    (N=256, K=266)
    gemm_k<1><<<dim3(MROWS/128, 2), blk, 0, stream>>>(sc, proj_w, proj_b, nullptr, h, HID, HID + EMB_D, HID + EMB_D);

    for (int l = 0; l < NLAYER; ++l) {
        // y = LN1(h)
        ln_k<<<dim3(MROWS/4), blk, 0, stream>>>(h, ln1_g + l*HID, ln1_b + l*HID, y);
        // qkvb = y @ slow_w[l]^T            (N=784, K=256) -> d_out scratch
        gemm_k<0><<<dim3(MROWS/128, 7), blk, 0, stream>>>(y, slow_w + (size_t)l*784*HID,
                                                          nullptr, nullptr, sc, 784, HID, HID);
        // softmax(q), softmax(k), sigmoid(beta) in place
        prep_k<<<dim3(MROWS*NHEAD/128), dim3(128), 0, stream>>>(sc);
        // sequential delta-rule scan -> o (into y)
        scan_k<<<dim3(B_SZ*NHEAD), dim3(64), 0, stream>>>(sc, y);
        // h = h + o @ out_w[l]^T            (N=256, K=256), in place
        gemm_k<4><<<dim3(MROWS/128, 2), blk, 0, stream>>>(y, out_w + (size_t)l*HID*HID,
                                                          nullptr, h, h, HID, HID, HID);
        // y = LN2(h)
        ln_k<<<dim3(MROWS/4), blk, 0, stream>>>(h, ln2_g + l*HID, ln2_b + l*HID, y);
        // FFN in two N=512 halves (hff half in d_out scratch)
        for (int half = 0; half < 2; ++half) {
            const float* w1 = ff1_w + (size_t)l*DFF*HID + (size_t)half*512*HID;
            const float* b1 = ff1_b + (size_t)l*DFF + half*512;
            const float* w2 = ff2_w + (size_t)l*HID*DFF + half*512;   // Wld=DFF
            // hff = relu(y @ w1^T + b1)     (N=512, K=256)
            gemm_k<3><<<dim3(MROWS/128, 4), blk, 0, stream>>>(y, w1, b1, nullptr, sc, 512, HID, HID);
            // h += hff @ w2^T (+b2 on half 0)  (N=256, K=512, Wld=1024)
            if (half == 0)
                gemm_k<5><<<dim3(MROWS/128, 2), blk, 0, stream>>>(sc, w2, ff2_b + l*HID, h, h, HID, 512, DFF);
            else
                gemm_k<4><<<dim3(MROWS/128, 2), blk, 0, stream>>>(sc, w2, nullptr, h, h, HID, 512, DFF);
        }
    }
    // out (FP32) = h @ outl_w^T + outl_b    (N=1623, K=256)
    gemm_k<1><<<dim3(MROWS/128, 13), blk, 0, stream>>>(h, outl_w, outl_b, nullptr, d_out, NCLS, HID, HID);
}

// Round 5
// 3152.521 us; speedup vs baseline: 2.1812x; 2.1812x over previous
//
#include <hip/hip_runtime.h>
#include <hip/hip_bf16.h>

// Problem constants
#define S_LEN  1024
#define B_SZ   32
#define IN_DIM 3072
#define HID    256
#define NHEAD  16
#define HDIM   16
#define DFF    1024
#define NLAYER 4
#define NCLS   1623
#define EMB_D  10
#define MROWS  (S_LEN * B_SZ)   // 32768
#define QSTRIDE 52               // padded per-step qkvb stride (16B aligned)

using bf16   = __hip_bfloat16;
using short8 = __attribute__((ext_vector_type(8))) short;
using f32x4  = __attribute__((ext_vector_type(4))) float;

#define GLOAD16(g, l) __builtin_amdgcn_global_load_lds(                        \
    (const __attribute__((address_space(1))) void*)(g),                        \
    (__attribute__((address_space(3))) void*)(l), 16, 0, 0)

// ---------------------------------------------------------------------------
// bf16 MFMA GEMM: C[M,N] = A[M,K]@W[N,K]^T.  BM=BN=128, BK=32, 256 thr/4 waves,
// each wave a 64x64 quadrant (4x4 frags of 16x16x32). K multiple of 32.
// W buffers padded to 128-multiple rows. FLAGS: 1 bias, 2 relu, 4 residual(fp32),
// 8 bf16-out, 16 permuted qkvb store (fp32, (b,h,s,52) layout).
// ---------------------------------------------------------------------------
template<int FLAGS>
__global__ __launch_bounds__(256) void mgemm(
    const bf16* __restrict__ A, const bf16* __restrict__ W,
    const float* __restrict__ bias, const float* R, void* C,
    int N, int K, int Wld)
{
    __shared__ bf16 sA[2][128 * 32];
    __shared__ bf16 sB[2][128 * 32];
    const int t    = threadIdx.x;
    const int lane = t & 63;
    const int wid  = t >> 6;
    const int wr   = wid >> 1, wc = wid & 1;
    const long bm  = (long)blockIdx.x * 128;
    const int  bn  = blockIdx.y * 128;
    const int  fr  = lane & 15;        // frag row/col
    const int  fg  = lane >> 4;        // k-group
    const int  row0 = t >> 2;          // staging row (0..63), +64 for 2nd issue
    const int  kq0  = (t & 3) << 3;    // staging k offset (elems)

    f32x4 acc[4][4];
#pragma unroll
    for (int m = 0; m < 4; ++m)
#pragma unroll
        for (int n = 0; n < 4; ++n)
#pragma unroll
            for (int r = 0; r < 4; ++r) acc[m][n][r] = 0.f;

    const int nkt = K >> 5;

    auto stage = [&](int buf, int kt) {
        const int k0 = kt << 5;
        GLOAD16(A + (bm + row0)      * (long)K   + k0 + kq0, &sA[buf][(t      ) * 8]);
        GLOAD16(A + (bm + row0 + 64) * (long)K   + k0 + kq0, &sA[buf][(t + 256) * 8]);
        GLOAD16(W + (long)(bn + row0)      * Wld + k0 + kq0, &sB[buf][(t      ) * 8]);
        GLOAD16(W + (long)(bn + row0 + 64) * Wld + k0 + kq0, &sB[buf][(t + 256) * 8]);
    };

    stage(0, 0);
    __syncthreads();
    for (int kt = 0; kt < nkt; ++kt) {
        const int cur = kt & 1;
        if (kt + 1 < nkt) stage(cur ^ 1, kt + 1);
        short8 af[4], bg[4];
#pragma unroll
        for (int m = 0; m < 4; ++m)
            af[m] = *(const short8*)&sA[cur][(wr * 64 + m * 16 + fr) * 32 + fg * 8];
#pragma unroll
        for (int n = 0; n < 4; ++n)
            bg[n] = *(const short8*)&sB[cur][(wc * 64 + n * 16 + fr) * 32 + fg * 8];
#pragma unroll
        for (int m = 0; m < 4; ++m)
#pragma unroll
            for (int n = 0; n < 4; ++n)
                acc[m][n] = __builtin_amdgcn_mfma_f32_16x16x32_bf16(
                    af[m], bg[n], acc[m][n], 0, 0, 0);
        __syncthreads();
    }

    // Epilogue. C/D layout (HW-verified): col = lane&15, row = (lane>>4)*4+reg.
    float bs[4];
#pragma unroll
    for (int n = 0; n < 4; ++n) {
        const int c = bn + wc * 64 + n * 16 + fr;
        bs[n] = ((FLAGS & 1) && c < N) ? bias[c] : 0.f;
    }
#pragma unroll
    for (int m = 0; m < 4; ++m) {
#pragma unroll
        for (int n = 0; n < 4; ++n) {
            const int c = bn + wc * 64 + n * 16 + fr;
            if (c < N) {
#pragma unroll
                for (int r = 0; r < 4; ++r) {
                    const long rw = bm + wr * 64 + m * 16 + fg * 4 + r;
                    float v = acc[m][n][r] + bs[n];
                    if (FLAGS & 2) v = fmaxf(v, 0.f);
                    if (FLAGS & 4) v += R[rw * N + c];
                    if (FLAGS & 16) {
                        const int s = (int)(rw >> 5), b = (int)(rw & 31);
                        const int hh = c / 49, cc = c - hh * 49;
                        ((float*)C)[((long)(b * 16 + hh) * 1024 + s) * QSTRIDE + cc] = v;
                    } else if (FLAGS & 8) {
                        ((bf16*)C)[rw * N + c] = __float2bfloat16(v);
                    } else {
                        ((float*)C)[rw * N + c] = v;
                    }
                }
            }
        }
    }
}

// ---------------------------------------------------------------------------
// fp32 -> bf16 bulk convert, count divisible by 8.
// ---------------------------------------------------------------------------
__global__ __launch_bounds__(256) void cvt8(const float* __restrict__ s,
                                            bf16* __restrict__ d, long n8)
{
    for (long i = (long)blockIdx.x * 256 + threadIdx.x; i < n8;
         i += (long)gridDim.x * 256) {
        const float4 a = ((const float4*)s)[i * 2];
        const float4 b = ((const float4*)s)[i * 2 + 1];
        alignas(16) bf16 t[8];
        t[0] = __float2bfloat16(a.x); t[1] = __float2bfloat16(a.y);
        t[2] = __float2bfloat16(a.z); t[3] = __float2bfloat16(a.w);
        t[4] = __float2bfloat16(b.x); t[5] = __float2bfloat16(b.y);
        t[6] = __float2bfloat16(b.z); t[7] = __float2bfloat16(b.w);
        ((short8*)d)[i] = *(const short8*)t;
    }
}

// ---------------------------------------------------------------------------
// fp32 [rows][cols] -> bf16 [prows][pcols], zero-padded.
// ---------------------------------------------------------------------------
__global__ __launch_bounds__(256) void cvtpad(const float* __restrict__ s,
                                              bf16* __restrict__ d,
                                              int rows, int cols, int prows, int pcols)
{
    const long tot = (long)prows * pcols;
    for (long i = (long)blockIdx.x * 256 + threadIdx.x; i < tot;
         i += (long)gridDim.x * 256) {
        const int r = (int)(i / pcols), c = (int)(i - (long)r * pcols);
        d[i] = (r < rows && c < cols) ? __float2bfloat16(s[(long)r * cols + c])
                                      : __float2bfloat16(0.f);
    }
}

// ---------------------------------------------------------------------------
// LayerNorm(256) -> bf16. One wave per row, 4 rows/block.
// ---------------------------------------------------------------------------
__global__ __launch_bounds__(256) void ln_b(
    const float* __restrict__ x, const float* __restrict__ g,
    const float* __restrict__ b, bf16* __restrict__ y)
{
    const int wave = threadIdx.x >> 6, lane = threadIdx.x & 63;
    const long row = (long)(blockIdx.x << 2) + wave;
    const float4 v = ((const float4*)(x + row * HID))[lane];
    float s = v.x + v.y + v.z + v.w;
#pragma unroll
    for (int m = 32; m; m >>= 1) s += __shfl_xor(s, m);
    const float mean = s * (1.f / 256.f);
    const float d0 = v.x - mean, d1 = v.y - mean, d2 = v.z - mean, d3 = v.w - mean;
    float ss = d0 * d0 + d1 * d1 + d2 * d2 + d3 * d3;
#pragma unroll
    for (int m = 32; m; m >>= 1) ss += __shfl_xor(ss, m);
    const float inv = rsqrtf(ss * (1.f / 256.f) + 1e-5f);
    const float4 gg = ((const float4*)g)[lane];
    const float4 bb = ((const float4*)b)[lane];
    alignas(8) bf16 t[4];
    t[0] = __float2bfloat16(fmaf(d0 * inv, gg.x, bb.x));
    t[1] = __float2bfloat16(fmaf(d1 * inv, gg.y, bb.y));
    t[2] = __float2bfloat16(fmaf(d2 * inv, gg.z, bb.z));
    t[3] = __float2bfloat16(fmaf(d3 * inv, gg.w, bb.w));
    *(ushort4*)((unsigned short*)y + row * HID + lane * 4) = *(const ushort4*)t;
}

// ---------------------------------------------------------------------------
// Concat: hcat[row] = [abuf[row] (256 bf16), bf16(emb[fb[row]]) (10), 0 (22)]
// ---------------------------------------------------------------------------
__global__ __launch_bounds__(64) void concat_b(
    const bf16* __restrict__ ab, const float* __restrict__ emb,
    const int* __restrict__ fb, bf16* __restrict__ hcat)
{
    const long row = blockIdx.x;
    const int lane = threadIdx.x;
    const ushort4 v = ((const ushort4*)(ab + row * HID))[lane];
    ((ushort4*)(hcat + row * 288))[lane] = v;
    if (lane < 32) {
        bf16 val = (lane < EMB_D)
            ? __float2bfloat16(emb[(long)fb[row] * EMB_D + lane])
            : __float2bfloat16(0.f);
        hcat[row * 288 + 256 + lane] = val;
    }
}

// ---------------------------------------------------------------------------
// prep over permuted qkvb (rows of QSTRIDE=52): softmax q[0:16], k[16:32],
// sigmoid beta[48]. One thread per row.
// ---------------------------------------------------------------------------
__global__ __launch_bounds__(256) void prep2(float* __restrict__ qkvb)
{
    const long r = (long)blockIdx.x * 256 + threadIdx.x;   // 524288 rows
    float* p = qkvb + r * QSTRIDE;
    float4 q[4], k[4];
#pragma unroll
    for (int i = 0; i < 4; ++i) { q[i] = *(float4*)(p + i * 4); k[i] = *(float4*)(p + 16 + i * 4); }
    float qm = -1e30f, km = -1e30f;
#pragma unroll
    for (int i = 0; i < 4; ++i) {
        qm = fmaxf(qm, fmaxf(fmaxf(q[i].x, q[i].y), fmaxf(q[i].z, q[i].w)));
        km = fmaxf(km, fmaxf(fmaxf(k[i].x, k[i].y), fmaxf(k[i].z, k[i].w)));
    }
    float qs = 0.f, ks = 0.f;
#pragma unroll
    for (int i = 0; i < 4; ++i) {
        q[i].x = __expf(q[i].x - qm); q[i].y = __expf(q[i].y - qm);
        q[i].z = __expf(q[i].z - qm); q[i].w = __expf(q[i].w - qm);
        qs += q[i].x + q[i].y + q[i].z + q[i].w;
        k[i].x = __expf(k[i].x - km); k[i].y = __expf(k[i].y - km);
        k[i].z = __expf(k[i].z - km); k[i].w = __expf(k[i].w - km);
        ks += k[i].x + k[i].y + k[i].z + k[i].w;
    }
    const float qi = 1.f / qs, ki = 1.f / ks;
#pragma unroll
    for (int i = 0; i < 4; ++i) {
        q[i].x *= qi; q[i].y *= qi; q[i].z *= qi; q[i].w *= qi;
        k[i].x *= ki; k[i].y *= ki; k[i].z *= ki; k[i].w *= ki;
        *(float4*)(p + i * 4) = q[i];
        *(float4*)(p + 16 + i * 4) = k[i];
    }
    p[48] = 1.f / (1.f + __expf(-p[48]));
}

// ---------------------------------------------------------------------------
// Delta-rule scan over permuted qkvb (contiguous per chain), 4-deep register
// prefetch. One wave per (b,h); lane: vi=l>>2 (v col), kg=l&3 (k quarter).
// Output o bf16 in (s,b,h*16+vi) layout.
// ---------------------------------------------------------------------------
__global__ __launch_bounds__(64) void scan2(
    const float* __restrict__ qkvb, bf16* __restrict__ o)
{
    const int bh = blockIdx.x;              // b*16 + h
    const int b = bh >> 4, hh = bh & 15;
    const int lane = threadIdx.x;
    const int vi = lane >> 2, kg = lane & 3;
    const float* pb = qkvb + (long)bh * S_LEN * QSTRIDE;
    const int qo = kg * 4, ko = 16 + kg * 4, vo = 32 + vi;

    float W0 = 0.f, W1 = 0.f, W2 = 0.f, W3 = 0.f;
    float4 pq[4], pk[4]; float pv[4], pt[4];
#pragma unroll
    for (int d = 0; d < 4; ++d) {
        const float* p = pb + (long)d * QSTRIDE;
        pq[d] = *(const float4*)(p + qo);
        pk[d] = *(const float4*)(p + ko);
        pv[d] = p[vo]; pt[d] = p[48];
    }
    bf16* po = o + (long)b * HID + hh * HDIM + vi;

    for (int s0 = 0; s0 < S_LEN; s0 += 4) {
#pragma unroll
        for (int u = 0; u < 4; ++u) {
            const int s = s0 + u;
            const float4 q = pq[u], k = pk[u];
            const float vt = pv[u], bt = pt[u];
            if (s + 4 < S_LEN) {                       // prefetch s+4 into slot u
                const float* p = pb + (long)(s + 4) * QSTRIDE;
                pq[u] = *(const float4*)(p + qo);
                pk[u] = *(const float4*)(p + ko);
                pv[u] = p[vo]; pt[u] = p[48];
            }
            float vold = 0.f;
            vold = fmaf(W0, k.x, vold); vold = fmaf(W1, k.y, vold);
            vold = fmaf(W2, k.z, vold); vold = fmaf(W3, k.w, vold);
            vold += __shfl_xor(vold, 1);
            vold += __shfl_xor(vold, 2);
            const float dv = bt * (vt - vold);
            W0 = fmaf(k.x, dv, W0); W1 = fmaf(k.y, dv, W1);
            W2 = fmaf(k.z, dv, W2); W3 = fmaf(k.w, dv, W3);
            float ov = 0.f;
            ov = fmaf(W0, q.x, ov); ov = fmaf(W1, q.y, ov);
            ov = fmaf(W2, q.z, ov); ov = fmaf(W3, q.w, ov);
            ov += __shfl_xor(ov, 1);
            ov += __shfl_xor(ov, 2);
            if (kg == 0) po[(long)s * (B_SZ * HID)] = __float2bfloat16(ov);
        }
    }
}

// ---------------------------------------------------------------------------
extern "C" void kernel_launch(void* const* d_in, const int* in_sizes, int n_in,
                              void* d_out, int out_size, void* d_ws, size_t ws_size,
                              hipStream_t stream)
{
    const float* x      = (const float*)d_in[0];
    const int*   fb     = (const int*)  d_in[1];
    const float* fc1_w  = (const float*)d_in[2];
    const float* fc1_b  = (const float*)d_in[3];
    const float* emb    = (const float*)d_in[4];
    const float* proj_w = (const float*)d_in[5];
    const float* proj_b = (const float*)d_in[6];
    const float* ln1_g  = (const float*)d_in[7];
    const float* ln1_b  = (const float*)d_in[8];
    const float* slow_w = (const float*)d_in[9];
    const float* out_w  = (const float*)d_in[10];
    const float* ln2_g  = (const float*)d_in[11];
    const float* ln2_b  = (const float*)d_in[12];
    const float* ff1_w  = (const float*)d_in[13];
    const float* ff1_b  = (const float*)d_in[14];
    const float* ff2_w  = (const float*)d_in[15];
    const float* ff2_b  = (const float*)d_in[16];
    const float* outl_w = (const float*)d_in[17];
    const float* outl_b = (const float*)d_in[18];

    // ---- workspace layout (59.5 MB) ----
    char* wp = (char*)d_ws;
    float* h    = (float*)wp;                 wp += (size_t)MROWS * HID * 4;   // 33.5MB
    bf16*  abuf = (bf16*)wp;                  wp += (size_t)MROWS * HID * 2;   // 16.8MB
    bf16*  fc1b = (bf16*)wp;                  wp += (size_t)HID * IN_DIM * 2;
    bf16*  projb= (bf16*)wp;                  wp += (size_t)HID * 288 * 2;
    bf16*  slowb= (bf16*)wp;                  wp += (size_t)NLAYER * 896 * HID * 2;
    bf16*  outwb= (bf16*)wp;                  wp += (size_t)NLAYER * HID * HID * 2;
    bf16*  ff1b = (bf16*)wp;                  wp += (size_t)NLAYER * DFF * HID * 2;
    bf16*  ff2b = (bf16*)wp;                  wp += (size_t)NLAYER * HID * DFF * 2;
    bf16*  outlb= (bf16*)wp;                  wp += (size_t)1664 * HID * 2;

    // ---- d_out scratch (212.9 MB), sequentially reused ----
    bf16*  xb   = (bf16*)d_out;               // 201.3MB, dead after fc1
    bf16*  hcat = (bf16*)d_out;               // 18.9MB, dead after proj
    float* qkvb = (float*)d_out;              // 109.1MB, dead after scan
    bf16*  hff  = (bf16*)d_out;               // 67.1MB, dead after ff2

    const dim3 blk(256);

    // ---- weight/input conversions (re-done every launch; deterministic) ----
    cvt8<<<dim3(4096), blk, 0, stream>>>(x, xb, (long)MROWS * IN_DIM / 8);
    cvt8<<<dim3(384),  blk, 0, stream>>>(fc1_w, fc1b, (long)HID * IN_DIM / 8);
    cvtpad<<<dim3(288), blk, 0, stream>>>(proj_w, projb, HID, HID + EMB_D, HID, 288);
    for (int l = 0; l < NLAYER; ++l)
        cvtpad<<<dim3(896), blk, 0, stream>>>(slow_w + (size_t)l * 784 * HID,
                                              slowb + (size_t)l * 896 * HID,
                                              784, HID, 896, HID);
    cvt8<<<dim3(128), blk, 0, stream>>>(out_w, outwb, (long)NLAYER * HID * HID / 8);
    cvt8<<<dim3(512), blk, 0, stream>>>(ff1_w, ff1b, (long)NLAYER * DFF * HID / 8);
    cvt8<<<dim3(512), blk, 0, stream>>>(ff2_w, ff2b, (long)NLAYER * HID * DFF / 8);
    cvtpad<<<dim3(1664), blk, 0, stream>>>(outl_w, outlb, NCLS, HID, 1664, HID);

    // fc1: abuf = bf16(x @ fc1_w^T + b)    N=256 K=3072
    mgemm<9><<<dim3(256, 2), blk, 0, stream>>>(xb, fc1b, fc1_b, nullptr, abuf,
                                               HID, IN_DIM, IN_DIM);
    // hcat = [abuf, emb[fb], 0-pad]  (K padded to 288)
    concat_b<<<dim3(MROWS), dim3(64), 0, stream>>>(abuf, emb, fb, hcat);
    // proj: h = hcat @ proj_w^T + b        N=256 K=288(266+pad)
    mgemm<1><<<dim3(256, 2), blk, 0, stream>>>(hcat, projb, proj_b, nullptr, h,
                                               HID, 288, 288);

    for (int l = 0; l < NLAYER; ++l) {
        ln_b<<<dim3(MROWS / 4), blk, 0, stream>>>(h, ln1_g + l * HID, ln1_b + l * HID, abuf);
        // qkvb (permuted (b,h,s,52) fp32)   N=784 K=256
        mgemm<16><<<dim3(256, 7), blk, 0, stream>>>(abuf, slowb + (size_t)l * 896 * HID,
                                                    nullptr, nullptr, qkvb, 784, HID, HID);
        prep2<<<dim3(2048), blk, 0, stream>>>(qkvb);
        scan2<<<dim3(B_SZ * NHEAD), dim3(64), 0, stream>>>(qkvb, abuf);
        // h += o @ out_w^T                  N=256 K=256
        mgemm<4><<<dim3(256, 2), blk, 0, stream>>>(abuf, outwb + (size_t)l * HID * HID,
                                                   nullptr, h, h, HID, HID, HID);
        ln_b<<<dim3(MROWS / 4), blk, 0, stream>>>(h, ln2_g + l * HID, ln2_b + l * HID, abuf);
        // hff = bf16(relu(y @ ff1^T + b1))  N=1024 K=256
        mgemm<11><<<dim3(256, 8), blk, 0, stream>>>(abuf, ff1b + (size_t)l * DFF * HID,
                                                    ff1_b + l * DFF, nullptr, hff,
                                                    DFF, HID, HID);
        // h += hff @ ff2^T + b2             N=256 K=1024
        mgemm<5><<<dim3(256, 2), blk, 0, stream>>>(hff, ff2b + (size_t)l * HID * DFF,
                                                   ff2_b + l * HID, h, h, HID, DFF, DFF);
    }
    // final: abuf = bf16(h); out = abuf @ outl_w^T + b  (fp32, N=1623 K=256)
    cvt8<<<dim3(1024), blk, 0, stream>>>(h, abuf, (long)MROWS * HID / 8);
    mgemm<1><<<dim3(256, 13), blk, 0, stream>>>(abuf, outlb, outl_b, nullptr, d_out,
                                                NCLS, HID, HID);
}

// Round 6
// 1981.914 us; speedup vs baseline: 3.4695x; 1.5906x over previous
//
#include <hip/hip_runtime.h>
#include <hip/hip_bf16.h>

// Problem constants
#define S_LEN  1024
#define B_SZ   32
#define IN_DIM 3072
#define HID    256
#define NHEAD  16
#define HDIM   16
#define DFF    1024
#define NLAYER 4
#define NCLS   1623
#define EMB_D  10
#define MROWS  (S_LEN * B_SZ)   // 32768
#define QSTRIDE 52               // padded per-step qkvb stride (16B aligned)
#define CHUNK  32                // scan steps staged per LDS chunk

using bf16   = __hip_bfloat16;
using short8 = __attribute__((ext_vector_type(8))) short;
using f32x4  = __attribute__((ext_vector_type(4))) float;

#define GLOAD16(g, l) __builtin_amdgcn_global_load_lds(                        \
    (const __attribute__((address_space(1))) void*)(g),                        \
    (__attribute__((address_space(3))) void*)(l), 16, 0, 0)

// ---------------------------------------------------------------------------
// bf16 MFMA GEMM: C[M,N] = A[M,K]@W[N,K]^T.  BM=BN=128, BK=32, 256 thr/4 waves,
// each wave a 64x64 quadrant (4x4 frags of 16x16x32). K multiple of 32.
// W buffers padded to 128-multiple rows. FLAGS: 1 bias, 2 relu, 4 residual(fp32),
// 8 bf16-out, 16 permuted qkvb store (fp32, (b,h,s,52) layout).
// ---------------------------------------------------------------------------
template<int FLAGS>
__global__ __launch_bounds__(256) void mgemm(
    const bf16* __restrict__ A, const bf16* __restrict__ W,
    const float* __restrict__ bias, const float* R, void* C,
    int N, int K, int Wld)
{
    __shared__ bf16 sA[2][128 * 32];
    __shared__ bf16 sB[2][128 * 32];
    const int t    = threadIdx.x;
    const int lane = t & 63;
    const int wid  = t >> 6;
    const int wr   = wid >> 1, wc = wid & 1;
    const long bm  = (long)blockIdx.x * 128;
    const int  bn  = blockIdx.y * 128;
    const int  fr  = lane & 15;        // frag row/col
    const int  fg  = lane >> 4;        // k-group
    const int  row0 = t >> 2;          // staging row (0..63), +64 for 2nd issue
    const int  kq0  = (t & 3) << 3;    // staging k offset (elems)

    f32x4 acc[4][4];
#pragma unroll
    for (int m = 0; m < 4; ++m)
#pragma unroll
        for (int n = 0; n < 4; ++n)
#pragma unroll
            for (int r = 0; r < 4; ++r) acc[m][n][r] = 0.f;

    const int nkt = K >> 5;

    auto stage = [&](int buf, int kt) {
        const int k0 = kt << 5;
        GLOAD16(A + (bm + row0)      * (long)K   + k0 + kq0, &sA[buf][(t      ) * 8]);
        GLOAD16(A + (bm + row0 + 64) * (long)K   + k0 + kq0, &sA[buf][(t + 256) * 8]);
        GLOAD16(W + (long)(bn + row0)      * Wld + k0 + kq0, &sB[buf][(t      ) * 8]);
        GLOAD16(W + (long)(bn + row0 + 64) * Wld + k0 + kq0, &sB[buf][(t + 256) * 8]);
    };

    stage(0, 0);
    __syncthreads();
    for (int kt = 0; kt < nkt; ++kt) {
        const int cur = kt & 1;
        if (kt + 1 < nkt) stage(cur ^ 1, kt + 1);
        short8 af[4], bg[4];
#pragma unroll
        for (int m = 0; m < 4; ++m)
            af[m] = *(const short8*)&sA[cur][(wr * 64 + m * 16 + fr) * 32 + fg * 8];
#pragma unroll
        for (int n = 0; n < 4; ++n)
            bg[n] = *(const short8*)&sB[cur][(wc * 64 + n * 16 + fr) * 32 + fg * 8];
#pragma unroll
        for (int m = 0; m < 4; ++m)
#pragma unroll
            for (int n = 0; n < 4; ++n)
                acc[m][n] = __builtin_amdgcn_mfma_f32_16x16x32_bf16(
                    af[m], bg[n], acc[m][n], 0, 0, 0);
        __syncthreads();
    }

    // Epilogue. C/D layout (HW-verified): col = lane&15, row = (lane>>4)*4+reg.
    float bs[4];
#pragma unroll
    for (int n = 0; n < 4; ++n) {
        const int c = bn + wc * 64 + n * 16 + fr;
        bs[n] = ((FLAGS & 1) && c < N) ? bias[c] : 0.f;
    }
#pragma unroll
    for (int m = 0; m < 4; ++m) {
#pragma unroll
        for (int n = 0; n < 4; ++n) {
            const int c = bn + wc * 64 + n * 16 + fr;
            if (c < N) {
#pragma unroll
                for (int r = 0; r < 4; ++r) {
                    const long rw = bm + wr * 64 + m * 16 + fg * 4 + r;
                    float v = acc[m][n][r] + bs[n];
                    if (FLAGS & 2) v = fmaxf(v, 0.f);
                    if (FLAGS & 4) v += R[rw * N + c];
                    if (FLAGS & 16) {
                        const int s = (int)(rw >> 5), b = (int)(rw & 31);
                        const int hh = c / 49, cc = c - hh * 49;
                        ((float*)C)[((long)(b * 16 + hh) * 1024 + s) * QSTRIDE + cc] = v;
                    } else if (FLAGS & 8) {
                        ((bf16*)C)[rw * N + c] = __float2bfloat16(v);
                    } else {
                        ((float*)C)[rw * N + c] = v;
                    }
                }
            }
        }
    }
}

// ---------------------------------------------------------------------------
// fp32 -> bf16 bulk convert, count divisible by 8.
// ---------------------------------------------------------------------------
__global__ __launch_bounds__(256) void cvt8(const float* __restrict__ s,
                                            bf16* __restrict__ d, long n8)
{
    for (long i = (long)blockIdx.x * 256 + threadIdx.x; i < n8;
         i += (long)gridDim.x * 256) {
        const float4 a = ((const float4*)s)[i * 2];
        const float4 b = ((const float4*)s)[i * 2 + 1];
        alignas(16) bf16 t[8];
        t[0] = __float2bfloat16(a.x); t[1] = __float2bfloat16(a.y);
        t[2] = __float2bfloat16(a.z); t[3] = __float2bfloat16(a.w);
        t[4] = __float2bfloat16(b.x); t[5] = __float2bfloat16(b.y);
        t[6] = __float2bfloat16(b.z); t[7] = __float2bfloat16(b.w);
        ((short8*)d)[i] = *(const short8*)t;
    }
}

// ---------------------------------------------------------------------------
// fp32 [rows][cols] -> bf16 [prows][pcols], zero-padded.
// ---------------------------------------------------------------------------
__global__ __launch_bounds__(256) void cvtpad(const float* __restrict__ s,
                                              bf16* __restrict__ d,
                                              int rows, int cols, int prows, int pcols)
{
    const long tot = (long)prows * pcols;
    for (long i = (long)blockIdx.x * 256 + threadIdx.x; i < tot;
         i += (long)gridDim.x * 256) {
        const int r = (int)(i / pcols), c = (int)(i - (long)r * pcols);
        d[i] = (r < rows && c < cols) ? __float2bfloat16(s[(long)r * cols + c])
                                      : __float2bfloat16(0.f);
    }
}

// ---------------------------------------------------------------------------
// LayerNorm(256) -> bf16. One wave per row, 4 rows/block.
// ---------------------------------------------------------------------------
__global__ __launch_bounds__(256) void ln_b(
    const float* __restrict__ x, const float* __restrict__ g,
    const float* __restrict__ b, bf16* __restrict__ y)
{
    const int wave = threadIdx.x >> 6, lane = threadIdx.x & 63;
    const long row = (long)(blockIdx.x << 2) + wave;
    const float4 v = ((const float4*)(x + row * HID))[lane];
    float s = v.x + v.y + v.z + v.w;
#pragma unroll
    for (int m = 32; m; m >>= 1) s += __shfl_xor(s, m);
    const float mean = s * (1.f / 256.f);
    const float d0 = v.x - mean, d1 = v.y - mean, d2 = v.z - mean, d3 = v.w - mean;
    float ss = d0 * d0 + d1 * d1 + d2 * d2 + d3 * d3;
#pragma unroll
    for (int m = 32; m; m >>= 1) ss += __shfl_xor(ss, m);
    const float inv = rsqrtf(ss * (1.f / 256.f) + 1e-5f);
    const float4 gg = ((const float4*)g)[lane];
    const float4 bb = ((const float4*)b)[lane];
    alignas(8) bf16 t[4];
    t[0] = __float2bfloat16(fmaf(d0 * inv, gg.x, bb.x));
    t[1] = __float2bfloat16(fmaf(d1 * inv, gg.y, bb.y));
    t[2] = __float2bfloat16(fmaf(d2 * inv, gg.z, bb.z));
    t[3] = __float2bfloat16(fmaf(d3 * inv, gg.w, bb.w));
    *(ushort4*)((unsigned short*)y + row * HID + lane * 4) = *(const ushort4*)t;
}

// ---------------------------------------------------------------------------
// Concat: hcat[row] = [abuf[row] (256 bf16), bf16(emb[fb[row]]) (10), 0 (22)]
// ---------------------------------------------------------------------------
__global__ __launch_bounds__(64) void concat_b(
    const bf16* __restrict__ ab, const float* __restrict__ emb,
    const int* __restrict__ fb, bf16* __restrict__ hcat)
{
    const long row = blockIdx.x;
    const int lane = threadIdx.x;
    const ushort4 v = ((const ushort4*)(ab + row * HID))[lane];
    ((ushort4*)(hcat + row * 288))[lane] = v;
    if (lane < 32) {
        bf16 val = (lane < EMB_D)
            ? __float2bfloat16(emb[(long)fb[row] * EMB_D + lane])
            : __float2bfloat16(0.f);
        hcat[row * 288 + 256 + lane] = val;
    }
}

// ---------------------------------------------------------------------------
// Delta-rule scan, v3: one wave (64 thr) per 4 chains; lane = (chain c = l>>4,
// v-col vi = l&15). Lane holds full W[:,vi] column (16 regs) -> NO cross-lane
// ops in the recurrence. qkvb chunks (CHUNK steps x 4 chains x 52 fp32) are
// staged into double-buffered LDS via global_load_lds; softmax(q,k) and
// sigmoid(beta) applied in-LDS per chunk (prep kernel fused away).
// Single-wave blocks: ordering via s_waitcnt only (no barrier -> the next
// chunk's loads stay in flight across the whole compute phase).
// LDS layout: row = s_local*4 + c, 52 floats/row; group base offsets mod 32
// banks = {0,20,8,28} -> broadcast b128 reads are conflict-free.
// ---------------------------------------------------------------------------
__global__ __launch_bounds__(64) void scan3(
    const float* __restrict__ qkvb, bf16* __restrict__ o)
{
    __shared__ float lds[2][4 * CHUNK * 52];   // 2 x 26624 B
    const int lane = threadIdx.x;
    const int c  = lane >> 4;        // chain within block
    const int vi = lane & 15;        // v column
    const int bh0 = blockIdx.x << 2; // 4 chains per block
    const int chain = bh0 + c;
    const int b = chain >> 4, hh = chain & 15;

    bf16* po = o + (long)b * HID + hh * HDIM + vi;

    // stage chunk ch into lds[buf]: 26 issues x 64 lanes x 16B
    auto stage = [&](int buf, int ch) {
#pragma unroll
        for (int i = 0; i < 26; ++i) {
            const int slot = i * 64 + lane;        // float4 slot in LDS
            const int row  = slot / 13;            // 0..127 = s_local*4 + cc
            const int f4   = slot - row * 13;
            const int cc   = row & 3, sl = row >> 2;
            const float* src = qkvb
                + (((long)(bh0 + cc) << 10) + ch * CHUNK + sl) * QSTRIDE + f4 * 4;
            GLOAD16(src, &lds[buf][i * 256]);
        }
    };

    float W[16];
#pragma unroll
    for (int j = 0; j < 16; ++j) W[j] = 0.f;

    stage(0, 0);
    const int nch = S_LEN / CHUNK;
    for (int ch = 0; ch < nch; ++ch) {
        const int buf = ch & 1;
        asm volatile("s_waitcnt vmcnt(0)" ::: "memory");   // chunk ch resident
        if (ch + 1 < nch) stage(buf ^ 1, ch + 1);          // prefetch next

        // fused prep: softmax q[0:16], k[16:32], sigmoid beta[48]; 2 rows/lane
        float* base = lds[buf];
#pragma unroll
        for (int rr = 0; rr < 2; ++rr) {
            float* p = base + (rr * 64 + lane) * 52;
            float4 q[4], k[4];
#pragma unroll
            for (int i = 0; i < 4; ++i) {
                q[i] = *(float4*)(p + i * 4);
                k[i] = *(float4*)(p + 16 + i * 4);
            }
            float qm = -1e30f, km = -1e30f;
#pragma unroll
            for (int i = 0; i < 4; ++i) {
                qm = fmaxf(qm, fmaxf(fmaxf(q[i].x, q[i].y), fmaxf(q[i].z, q[i].w)));
                km = fmaxf(km, fmaxf(fmaxf(k[i].x, k[i].y), fmaxf(k[i].z, k[i].w)));
            }
            float qs = 0.f, ks = 0.f;
#pragma unroll
            for (int i = 0; i < 4; ++i) {
                q[i].x = __expf(q[i].x - qm); q[i].y = __expf(q[i].y - qm);
                q[i].z = __expf(q[i].z - qm); q[i].w = __expf(q[i].w - qm);
                qs += q[i].x + q[i].y + q[i].z + q[i].w;
                k[i].x = __expf(k[i].x - km); k[i].y = __expf(k[i].y - km);
                k[i].z = __expf(k[i].z - km); k[i].w = __expf(k[i].w - km);
                ks += k[i].x + k[i].y + k[i].z + k[i].w;
            }
            const float qi = 1.f / qs, ki = 1.f / ks;
#pragma unroll
            for (int i = 0; i < 4; ++i) {
                q[i].x *= qi; q[i].y *= qi; q[i].z *= qi; q[i].w *= qi;
                k[i].x *= ki; k[i].y *= ki; k[i].z *= ki; k[i].w *= ki;
                *(float4*)(p + i * 4) = q[i];
                *(float4*)(p + 16 + i * 4) = k[i];
            }
            p[48] = 1.f / (1.f + __expf(-p[48]));
        }
        asm volatile("s_waitcnt lgkmcnt(0)" ::: "memory"); // prep visible wave-wide

        // recurrence over CHUNK steps
        const int sg0 = ch * CHUNK;
        for (int sl = 0; sl < CHUNK; ++sl) {
            const float* p = base + (sl * 4 + c) * 52;
            const float4 q0 = *(const float4*)(p);
            const float4 q1 = *(const float4*)(p + 4);
            const float4 q2 = *(const float4*)(p + 8);
            const float4 q3 = *(const float4*)(p + 12);
            const float4 k0 = *(const float4*)(p + 16);
            const float4 k1 = *(const float4*)(p + 20);
            const float4 k2 = *(const float4*)(p + 24);
            const float4 k3 = *(const float4*)(p + 28);
            const float vt = p[32 + vi];
            const float bt = p[48];

            // v_old(vi) = sum_j W[j]*k[j]  (4 parallel partial chains + tree)
            float pa = fmaf(W[3],  k0.w, fmaf(W[2],  k0.z, fmaf(W[1],  k0.y, W[0]  * k0.x)));
            float pb = fmaf(W[7],  k1.w, fmaf(W[6],  k1.z, fmaf(W[5],  k1.y, W[4]  * k1.x)));
            float pc = fmaf(W[11], k2.w, fmaf(W[10], k2.z, fmaf(W[9],  k2.y, W[8]  * k2.x)));
            float pd = fmaf(W[15], k3.w, fmaf(W[14], k3.z, fmaf(W[13], k3.y, W[12] * k3.x)));
            const float vold = (pa + pb) + (pc + pd);
            const float dv = bt * (vt - vold);
            // W[j] += k[j]*dv  (16 independent)
            W[0]  = fmaf(k0.x, dv, W[0]);  W[1]  = fmaf(k0.y, dv, W[1]);
            W[2]  = fmaf(k0.z, dv, W[2]);  W[3]  = fmaf(k0.w, dv, W[3]);
            W[4]  = fmaf(k1.x, dv, W[4]);  W[5]  = fmaf(k1.y, dv, W[5]);
            W[6]  = fmaf(k1.z, dv, W[6]);  W[7]  = fmaf(k1.w, dv, W[7]);
            W[8]  = fmaf(k2.x, dv, W[8]);  W[9]  = fmaf(k2.y, dv, W[9]);
            W[10] = fmaf(k2.z, dv, W[10]); W[11] = fmaf(k2.w, dv, W[11]);
            W[12] = fmaf(k3.x, dv, W[12]); W[13] = fmaf(k3.y, dv, W[13]);
            W[14] = fmaf(k3.z, dv, W[14]); W[15] = fmaf(k3.w, dv, W[15]);
            // o(vi) = sum_j W[j]*q[j]
            float oa = fmaf(W[3],  q0.w, fmaf(W[2],  q0.z, fmaf(W[1],  q0.y, W[0]  * q0.x)));
            float ob = fmaf(W[7],  q1.w, fmaf(W[6],  q1.z, fmaf(W[5],  q1.y, W[4]  * q1.x)));
            float oc = fmaf(W[11], q2.w, fmaf(W[10], q2.z, fmaf(W[9],  q2.y, W[8]  * q2.x)));
            float od = fmaf(W[15], q3.w, fmaf(W[14], q3.z, fmaf(W[13], q3.y, W[12] * q3.x)));
            const float ov = (oa + ob) + (oc + od);
            po[(long)(sg0 + sl) * (B_SZ * HID)] = __float2bfloat16(ov);
        }
    }
}

// ---------------------------------------------------------------------------
extern "C" void kernel_launch(void* const* d_in, const int* in_sizes, int n_in,
                              void* d_out, int out_size, void* d_ws, size_t ws_size,
                              hipStream_t stream)
{
    const float* x      = (const float*)d_in[0];
    const int*   fb     = (const int*)  d_in[1];
    const float* fc1_w  = (const float*)d_in[2];
    const float* fc1_b  = (const float*)d_in[3];
    const float* emb    = (const float*)d_in[4];
    const float* proj_w = (const float*)d_in[5];
    const float* proj_b = (const float*)d_in[6];
    const float* ln1_g  = (const float*)d_in[7];
    const float* ln1_b  = (const float*)d_in[8];
    const float* slow_w = (const float*)d_in[9];
    const float* out_w  = (const float*)d_in[10];
    const float* ln2_g  = (const float*)d_in[11];
    const float* ln2_b  = (const float*)d_in[12];
    const float* ff1_w  = (const float*)d_in[13];
    const float* ff1_b  = (const float*)d_in[14];
    const float* ff2_w  = (const float*)d_in[15];
    const float* ff2_b  = (const float*)d_in[16];
    const float* outl_w = (const float*)d_in[17];
    const float* outl_b = (const float*)d_in[18];

    // ---- workspace layout (59.5 MB) ----
    char* wp = (char*)d_ws;
    float* h    = (float*)wp;                 wp += (size_t)MROWS * HID * 4;   // 33.5MB
    bf16*  abuf = (bf16*)wp;                  wp += (size_t)MROWS * HID * 2;   // 16.8MB
    bf16*  fc1b = (bf16*)wp;                  wp += (size_t)HID * IN_DIM * 2;
    bf16*  projb= (bf16*)wp;                  wp += (size_t)HID * 288 * 2;
    bf16*  slowb= (bf16*)wp;                  wp += (size_t)NLAYER * 896 * HID * 2;
    bf16*  outwb= (bf16*)wp;                  wp += (size_t)NLAYER * HID * HID * 2;
    bf16*  ff1b = (bf16*)wp;                  wp += (size_t)NLAYER * DFF * HID * 2;
    bf16*  ff2b = (bf16*)wp;                  wp += (size_t)NLAYER * HID * DFF * 2;
    bf16*  outlb= (bf16*)wp;                  wp += (size_t)1664 * HID * 2;

    // ---- d_out scratch (212.9 MB), sequentially reused ----
    bf16*  xb   = (bf16*)d_out;               // 201.3MB, dead after fc1
    bf16*  hcat = (bf16*)d_out;               // 18.9MB, dead after proj
    float* qkvb = (float*)d_out;              // 109.1MB, dead after scan
    bf16*  hff  = (bf16*)d_out;               // 67.1MB, dead after ff2

    const dim3 blk(256);

    // ---- weight/input conversions (re-done every launch; deterministic) ----
    cvt8<<<dim3(4096), blk, 0, stream>>>(x, xb, (long)MROWS * IN_DIM / 8);
    cvt8<<<dim3(384),  blk, 0, stream>>>(fc1_w, fc1b, (long)HID * IN_DIM / 8);
    cvtpad<<<dim3(288), blk, 0, stream>>>(proj_w, projb, HID, HID + EMB_D, HID, 288);
    for (int l = 0; l < NLAYER; ++l)
        cvtpad<<<dim3(896), blk, 0, stream>>>(slow_w + (size_t)l * 784 * HID,
                                              slowb + (size_t)l * 896 * HID,
                                              784, HID, 896, HID);
    cvt8<<<dim3(128), blk, 0, stream>>>(out_w, outwb, (long)NLAYER * HID * HID / 8);
    cvt8<<<dim3(512), blk, 0, stream>>>(ff1_w, ff1b, (long)NLAYER * DFF * HID / 8);
    cvt8<<<dim3(512), blk, 0, stream>>>(ff2_w, ff2b, (long)NLAYER * HID * DFF / 8);
    cvtpad<<<dim3(1664), blk, 0, stream>>>(outl_w, outlb, NCLS, HID, 1664, HID);

    // fc1: abuf = bf16(x @ fc1_w^T + b)    N=256 K=3072
    mgemm<9><<<dim3(256, 2), blk, 0, stream>>>(xb, fc1b, fc1_b, nullptr, abuf,
                                               HID, IN_DIM, IN_DIM);
    // hcat = [abuf, emb[fb], 0-pad]  (K padded to 288)
    concat_b<<<dim3(MROWS), dim3(64), 0, stream>>>(abuf, emb, fb, hcat);
    // proj: h = hcat @ proj_w^T + b        N=256 K=288(266+pad)
    mgemm<1><<<dim3(256, 2), blk, 0, stream>>>(hcat, projb, proj_b, nullptr, h,
                                               HID, 288, 288);

    for (int l = 0; l < NLAYER; ++l) {
        ln_b<<<dim3(MROWS / 4), blk, 0, stream>>>(h, ln1_g + l * HID, ln1_b + l * HID, abuf);
        // qkvb (permuted (b,h,s,52) fp32, RAW — softmax fused into scan3)
        mgemm<16><<<dim3(256, 7), blk, 0, stream>>>(abuf, slowb + (size_t)l * 896 * HID,
                                                    nullptr, nullptr, qkvb, 784, HID, HID);
        scan3<<<dim3(B_SZ * NHEAD / 4), dim3(64), 0, stream>>>(qkvb, abuf);
        // h += o @ out_w^T                  N=256 K=256
        mgemm<4><<<dim3(256, 2), blk, 0, stream>>>(abuf, outwb + (size_t)l * HID * HID,
                                                   nullptr, h, h, HID, HID, HID);
        ln_b<<<dim3(MROWS / 4), blk, 0, stream>>>(h, ln2_g + l * HID, ln2_b + l * HID, abuf);
        // hff = bf16(relu(y @ ff1^T + b1))  N=1024 K=256
        mgemm<11><<<dim3(256, 8), blk, 0, stream>>>(abuf, ff1b + (size_t)l * DFF * HID,
                                                    ff1_b + l * DFF, nullptr, hff,
                                                    DFF, HID, HID);
        // h += hff @ ff2^T + b2             N=256 K=1024
        mgemm<5><<<dim3(256, 2), blk, 0, stream>>>(hff, ff2b + (size_t)l * HID * DFF,
                                                   ff2_b + l * HID, h, h, HID, DFF, DFF);
    }
    // final: abuf = bf16(h); out = abuf @ outl_w^T + b  (fp32, N=1623 K=256)
    cvt8<<<dim3(1024), blk, 0, stream>>>(h, abuf, (long)MROWS * HID / 8);
    mgemm<1><<<dim3(256, 13), blk, 0, stream>>>(abuf, outlb, outl_b, nullptr, d_out,
                                                NCLS, HID, HID);
}